// Round 14
// baseline (201.808 us; speedup 1.0000x reference)
//
#include <hip/hip_runtime.h>

typedef unsigned short u16;
typedef __attribute__((ext_vector_type(8))) short short8;
typedef __attribute__((ext_vector_type(4))) short s16x4;
typedef __attribute__((ext_vector_type(4))) float f32x4;
typedef __attribute__((ext_vector_type(2))) unsigned int u32x2;

// ws float-index offsets
#define OFF_U     0       // [4][4][64] folded value vectors (tag,h,k)
#define OFF_CV    1024    // [4][4]
#define OFF_CONST 1040
#define OFF_CTAG  1044    // [4] per-tag bo.wfh sums
#define OFF_BA    1056    // [272] fp32 bias for WA cols
#define OFF_BB    1328    // [272]
// ws byte offsets (16B-aligned)
#define OFF_WA_B    6400     // u16 [17][2][64][8]  WA frag-ordered
#define OFF_WB_B    41216    // u16 [17][2][64][8]  WB frag-ordered
#define OFF_W2P_B   76032    // u16 [8][32][64][8]  w2 in frag order
#define OFF_W3P_B   338176   // u16 [8][16][64][8]  w3 in frag order
#define OFF_TOK_B   469248   // u16 tokens, D-MAJOR: [8][65536][64]

#define P_STRIDE 280
#define PSIDE2   (64 * P_STRIDE)   // 16-elem blocks: 64 rows per side

// sqrt(log2(e)): Q and K blocks of WA/WB both scaled by this in prep_pack,
// so QK^T MFMA emits log2e*score and softmax uses raw hardware 2^x.
#define SQL2E 1.2011224087864498f

#if __has_builtin(__builtin_amdgcn_exp2f)
#define EXP2(x) __builtin_amdgcn_exp2f(x)
#else
#define EXP2(x) exp2f(x)
#endif

// tokens scratch column swizzle (R28 retest — R18's failure is now attributed
// to cvtpk-asm, proven by R19/R20 failing WITHOUT this swizzle). XOR row bits
// into the 8-u16 (16B) block index: bijective within the 136-u16 row
// (cols < 128), preserves 8B/16B alignment (cols are 0 mod 4 / 0 mod 8 and
// the XOR adds multiples of 8). Applied to ALL scratch accesses.
#define SCOL(row, col) ((col) ^ (((row) & 7) << 3))

static __device__ __forceinline__ u16 f2bf(float f) {
  unsigned int bits = __float_as_uint(f);
  bits += 0x7fffu + ((bits >> 16) & 1u);
  return (u16)(bits >> 16);
}
// COMPILER-NATIVE packed f32->bf16 (RNE) via the __bf16 IR type (tokens).
// R18-R20 lesson: NEVER hand-write cvt_pk asm in a kernel that also issues
// MFMA — data-dependent garbage. Native IR = safe.
static __device__ __forceinline__ unsigned pk2(float lo, float hi) {
  union { __bf16 h[2]; unsigned u; } c;
  c.h[0] = (__bf16)lo;
  c.h[1] = (__bf16)hi;
  return c.u;
}
// asm cvtpk retained ONLY for attn_kernel (harness-proven there, R3/R8).
static __device__ __forceinline__ unsigned cvtpk(float lo, float hi) {
  unsigned r;
  asm("v_cvt_pk_bf16_f32 %0, %1, %2" : "=v"(r) : "v"(lo), "v"(hi));
  return r;
}

// ---------------------------------------------------------------- prep 1: fold
// R27: own kernel (R12 inline-fold regressed prep_pack 5 -> 67us: the
// LDS-shared v, computed once per tag, is the whole point).
__global__ __launch_bounds__(64) void prep_fold(
    const float* __restrict__ win_sa, const float* __restrict__ bin_sa,
    const float* __restrict__ wo_sa,  const float* __restrict__ bo_sa,
    const float* __restrict__ win_sb, const float* __restrict__ bin_sb,
    const float* __restrict__ wo_sb,  const float* __restrict__ bo_sb,
    const float* __restrict__ win_ca, const float* __restrict__ bin_ca,
    const float* __restrict__ wo_ca,  const float* __restrict__ bo_ca,
    const float* __restrict__ win_cb, const float* __restrict__ bin_cb,
    const float* __restrict__ wo_cb,  const float* __restrict__ bo_cb,
    const float* __restrict__ Wf, float* __restrict__ ws) {
  __shared__ float v_lds[64];
  const int t = threadIdx.x;
  const int tag = blockIdx.x;
  const float* wins[4] = {win_sa, win_sb, win_ca, win_cb};
  const float* bins[4] = {bin_sa, bin_sb, bin_ca, bin_cb};
  const float* wos[4]  = {wo_sa, wo_sb, wo_ca, wo_cb};
  const float* bos[4]  = {bo_sa, bo_sb, bo_ca, bo_cb};
  const float* wfh = Wf + ((tag == 0 || tag == 2) ? 0 : 64);
  float v = 0.f;
#pragma unroll
  for (int e = 0; e < 64; e++) v += wos[tag][e * 64 + t] * wfh[e];
  v_lds[t] = v;
  __syncthreads();
#pragma unroll
  for (int h = 0; h < 4; h++) {
    float u = 0.f;
#pragma unroll
    for (int dp = 0; dp < 16; dp++)
      u += wins[tag][(128 + h * 16 + dp) * 64 + t] * v_lds[h * 16 + dp];
    ws[OFF_U + tag * 256 + h * 64 + t] = u;
  }
  if (t < 4) {
    float cv = 0.f;
#pragma unroll
    for (int dp = 0; dp < 16; dp++)
      cv += bins[tag][128 + t * 16 + dp] * v_lds[t * 16 + dp];
    ws[OFF_CV + tag * 4 + t] = cv;
  }
  if (t == 0) {
    float c = 0.f;
#pragma unroll
    for (int e = 0; e < 64; e++) c += bos[tag][e] * wfh[e];
    ws[OFF_CTAG + tag] = c;
  }
}

// ---------------------------------------------------------------- prep 2: pack
__global__ __launch_bounds__(256) void prep_pack(
    const float* __restrict__ w2, const float* __restrict__ w3,
    const float* __restrict__ win_sa, const float* __restrict__ win_sb,
    const float* __restrict__ win_ca, const float* __restrict__ win_cb,
    const float* __restrict__ bin_sa, const float* __restrict__ bin_sb,
    const float* __restrict__ bin_ca, const float* __restrict__ bin_cb,
    const float* __restrict__ bf,
    float* __restrict__ ws, u16* __restrict__ w2p, u16* __restrict__ w3p,
    u16* __restrict__ WA, u16* __restrict__ WB) {
  int idx = blockIdx.x * 256 + threadIdx.x;
  if (idx < 131072) {               // w2p[d][ks*8+nt][lane][j]
    int d = idx >> 14, rem = idx & 16383;
    int f = rem >> 9, ks = f >> 3, nt = f & 7;
    int r2 = rem & 511, l = r2 >> 3, j = r2 & 7;
    int quad = l >> 4, m15 = l & 15;
    w2p[idx] = f2bf(w2[(d * 128 + nt * 16 + m15) * 128 + ks * 32 + quad * 8 + j]);
  } else if (idx < 196608) {        // w3p[d][ks*4+nt][lane][j]
    int i = idx - 131072;
    int d = i >> 13, rem = i & 8191;
    int f = rem >> 9, ks = f >> 2, nt = f & 3;
    int r2 = rem & 511, l = r2 >> 3, j = r2 & 7;
    int quad = l >> 4, m15 = l & 15;
    w3p[i] = f2bf(w3[(d * 64 + nt * 16 + m15) * 128 + ks * 32 + quad * 8 + j]);
  } else if (idx < 214016) {        // WAf [17][2][64][8]
    int i = idx - 196608;
    int nt = i >> 10, rem = i & 1023;
    int half = rem >> 9, r2 = rem & 511, l = r2 >> 3, j = r2 & 7;
    int n = nt * 16 + (l & 15), k = half * 32 + (l >> 4) * 8 + j;
    float v;
    if (n < 64)       v = win_sa[n * 64 + k] * 0.25f;
    else if (n < 128) v = win_sa[n * 64 + k];
    else if (n < 192) v = win_ca[(n - 128) * 64 + k] * 0.25f;
    else if (n < 256) v = win_cb[(n - 128) * 64 + k];
    else if (n < 260) v = ws[OFF_U + 0 * 256 + (n - 256) * 64 + k];
    else if (n < 264) v = ws[OFF_U + 3 * 256 + (n - 260) * 64 + k];
    else              v = 0.f;
    if (n < 256) v *= SQL2E;        // fold exp->exp2 scale into Q and K blocks
    WA[i] = f2bf(v);
  } else if (idx < 231424) {        // WBf [17][2][64][8]
    int i = idx - 214016;
    int nt = i >> 10, rem = i & 1023;
    int half = rem >> 9, r2 = rem & 511, l = r2 >> 3, j = r2 & 7;
    int n = nt * 16 + (l & 15), k = half * 32 + (l >> 4) * 8 + j;
    float v;
    if (n < 64)       v = win_sb[n * 64 + k] * 0.25f;
    else if (n < 128) v = win_sb[n * 64 + k];
    else if (n < 192) v = win_cb[(n - 128) * 64 + k] * 0.25f;
    else if (n < 256) v = win_ca[(n - 128) * 64 + k];
    else if (n < 260) v = ws[OFF_U + 1 * 256 + (n - 256) * 64 + k];
    else if (n < 264) v = ws[OFF_U + 2 * 256 + (n - 260) * 64 + k];
    else              v = 0.f;
    if (n < 256) v *= SQL2E;        // fold exp->exp2 scale into Q and K blocks
    WB[i] = f2bf(v);
  } else if (idx < 231696) {        // bA
    int n = idx - 231424;
    float v;
    if (n < 64)       v = bin_sa[n] * 0.25f;
    else if (n < 128) v = bin_sa[n];
    else if (n < 192) v = bin_ca[n - 128] * 0.25f;
    else if (n < 256) v = bin_cb[n - 128];
    else if (n < 260) v = ws[OFF_CV + 0 * 4 + (n - 256)];
    else if (n < 264) v = ws[OFF_CV + 3 * 4 + (n - 260)];
    else              v = 0.f;
    if (n < 256) v *= SQL2E;
    ws[OFF_BA + n] = v;
  } else if (idx < 231968) {        // bB
    int n = idx - 231696;
    float v;
    if (n < 64)       v = bin_sb[n] * 0.25f;
    else if (n < 128) v = bin_sb[n];
    else if (n < 192) v = bin_cb[n - 128] * 0.25f;
    else if (n < 256) v = bin_ca[n - 128];
    else if (n < 260) v = ws[OFF_CV + 1 * 4 + (n - 256)];
    else if (n < 264) v = ws[OFF_CV + 2 * 4 + (n - 260)];
    else              v = 0.f;
    if (n < 256) v *= SQL2E;
    ws[OFF_BB + n] = v;
  } else if (idx == 231968) {
    ws[OFF_CONST] = 0.5f * (ws[OFF_CTAG] + ws[OFF_CTAG + 1] +
                            ws[OFF_CTAG + 2] + ws[OFF_CTAG + 3]) + bf[0];
  }
}

// ---------------------------------------------------------------- tokens (MFMA)
// R28: R22 structure (M=32/wave, w2/w3 streamed from L2) + SCOL swizzle on
// scratch (clean retest — the R18 failure was cvtpk-asm, not the swizzle;
// targets the 2.6M-cycle 4-way bank alias on ep2/ep3 8B writes).
__global__ __launch_bounds__(256, 4) void tokens_kernel(
    const float* __restrict__ x, const float* __restrict__ w1,
    const float* __restrict__ b1, const float* __restrict__ b2,
    const float* __restrict__ b3, const u16* __restrict__ w2p,
    const u16* __restrict__ w3p, u16* __restrict__ tok_out) {
  __shared__ __align__(16) u16 scratch[4][32 * 136];   // h2s, then store-stage
  const int t = threadIdx.x;
  const int wave = t >> 6, lane = t & 63;
  const int m15 = lane & 15, quad = lane >> 4;
  const int d = blockIdx.x >> 9;          // d-major: co-resident blocks share w2[d]
  const int g = blockIdx.x & 511;
  const int b0 = g * 128 + wave * 32;
  const float xv0 = x[(size_t)(b0 + m15) * 8 + d];
  const float xv1 = x[(size_t)(b0 + 16 + m15) * 8 + d];

  // ---- layer2 MFMA: B-frags streamed (frag-ordered w2p), A rebuilt per ks
  const u16* w2base = w2p + d * 16384 + lane * 8;
  f32x4 acc2[2][8];
#pragma unroll
  for (int mt = 0; mt < 2; mt++)
#pragma unroll
    for (int nt = 0; nt < 8; nt++) acc2[mt][nt] = (f32x4){0.f, 0.f, 0.f, 0.f};
#pragma unroll
  for (int ks = 0; ks < 4; ks++) {
    const float* w1p = w1 + d * 128 + ks * 32 + quad * 8;
    const float* b1p = b1 + d * 128 + ks * 32 + quad * 8;
    float4 wa = *(const float4*)w1p, wb = *(const float4*)(w1p + 4);
    float4 ba = *(const float4*)b1p, bb = *(const float4*)(b1p + 4);
    union { short8 s; unsigned u[4]; } a0, a1;
    a0.u[0] = pk2(__sinf(xv0 * wa.x + ba.x), __sinf(xv0 * wa.y + ba.y));
    a0.u[1] = pk2(__sinf(xv0 * wa.z + ba.z), __sinf(xv0 * wa.w + ba.w));
    a0.u[2] = pk2(__sinf(xv0 * wb.x + bb.x), __sinf(xv0 * wb.y + bb.y));
    a0.u[3] = pk2(__sinf(xv0 * wb.z + bb.z), __sinf(xv0 * wb.w + bb.w));
    a1.u[0] = pk2(__sinf(xv1 * wa.x + ba.x), __sinf(xv1 * wa.y + ba.y));
    a1.u[1] = pk2(__sinf(xv1 * wa.z + ba.z), __sinf(xv1 * wa.w + ba.w));
    a1.u[2] = pk2(__sinf(xv1 * wb.x + bb.x), __sinf(xv1 * wb.y + bb.y));
    a1.u[3] = pk2(__sinf(xv1 * wb.z + bb.z), __sinf(xv1 * wb.w + bb.w));
#pragma unroll
    for (int nt = 0; nt < 8; nt++) {
      short8 bfr = *(const short8*)(w2base + (ks * 8 + nt) * 512);
      // swapped: C[m = w2-col][n = token]; lane holds token m15, rows quad*4+r
      acc2[0][nt] = __builtin_amdgcn_mfma_f32_16x16x32_bf16(bfr, a0.s, acc2[0][nt], 0, 0, 0);
      acc2[1][nt] = __builtin_amdgcn_mfma_f32_16x16x32_bf16(bfr, a1.s, acc2[1][nt], 0, 0, 0);
    }
  }
  // ---- ep2 -> wave-private scratch, packed 8B writes (SCOL-swizzled)
#pragma unroll
  for (int nt = 0; nt < 8; nt++) {
    float4 bi = *(const float4*)(b2 + d * 128 + nt * 16 + quad * 4);
#pragma unroll
    for (int mt = 0; mt < 2; mt++) {
      const int row = mt * 16 + m15;
      u32x2 pk;
      pk[0] = pk2(__sinf(acc2[mt][nt][0] + bi.x), __sinf(acc2[mt][nt][1] + bi.y));
      pk[1] = pk2(__sinf(acc2[mt][nt][2] + bi.z), __sinf(acc2[mt][nt][3] + bi.w));
      *(u32x2*)&scratch[wave][row * 136 + SCOL(row, nt * 16 + quad * 4)] = pk;
    }
  }
  // ---- layer3 MFMA: A from LDS (SCOL-swizzled reads), B streamed (w3p)
  const u16* w3base = w3p + d * 8192 + lane * 8;
  f32x4 acc3[2][4];
#pragma unroll
  for (int mt = 0; mt < 2; mt++)
#pragma unroll
    for (int nt = 0; nt < 4; nt++) acc3[mt][nt] = (f32x4){0.f, 0.f, 0.f, 0.f};
#pragma unroll
  for (int ks = 0; ks < 4; ks++) {
    short8 af0 = *(const short8*)&scratch[wave][m15 * 136 +
                                               SCOL(m15, ks * 32 + quad * 8)];
    short8 af1 = *(const short8*)&scratch[wave][(16 + m15) * 136 +
                                               SCOL(16 + m15, ks * 32 + quad * 8)];
#pragma unroll
    for (int nt = 0; nt < 4; nt++) {
      short8 bfr = *(const short8*)(w3base + (ks * 4 + nt) * 512);
      acc3[0][nt] = __builtin_amdgcn_mfma_f32_16x16x32_bf16(bfr, af0, acc3[0][nt], 0, 0, 0);
      acc3[1][nt] = __builtin_amdgcn_mfma_f32_16x16x32_bf16(bfr, af1, acc3[1][nt], 0, 0, 0);
    }
  }
  // ---- ep3: packed re-stage (same-wave order-safe), SCOL-swizzled
#pragma unroll
  for (int nt = 0; nt < 4; nt++) {
    float4 bi = *(const float4*)(b3 + d * 64 + nt * 16 + quad * 4);
#pragma unroll
    for (int mt = 0; mt < 2; mt++) {
      const int row = mt * 16 + m15;
      u32x2 pk;
      pk[0] = pk2(acc3[mt][nt][0] + bi.x, acc3[mt][nt][1] + bi.y);
      pk[1] = pk2(acc3[mt][nt][2] + bi.z, acc3[mt][nt][3] + bi.w);
      *(u32x2*)&scratch[wave][row * 136 + SCOL(row, nt * 16 + quad * 4)] = pk;
    }
  }
  {
    int chunk = lane & 7;
#pragma unroll
    for (int it = 0; it < 4; it++) {
      int row_l = (lane >> 3) + it * 8;
      short8 v = *(const short8*)&scratch[wave][row_l * 136 +
                                               SCOL(row_l, chunk * 8)];
      *(short8*)(tok_out + ((size_t)(d * 65536 + b0 + row_l)) * 64 + chunk * 8) = v;
    }
  }
}

// ---------------------------------------------------------------- attention
// R26/R27 (frozen): R17/R8 structure + balanced 8.5/8.5 stage-A split;
// softmax via hardware 2^x (scores pre-scaled by log2e in prep_pack).
// R23 512-thr split regressed; don't re-split.
__global__ __launch_bounds__(256, 2) void attn_kernel(
    const float* __restrict__ ws, const u16* __restrict__ tok,
    const u16* __restrict__ WA, const u16* __restrict__ WB,
    float* __restrict__ out) {
  __shared__ __align__(16) u16 P[2 * PSIDE2];     // 70 KB
  __shared__ __align__(16) float Vf[2][64][12];   // 6 KB
  const int t = threadIdx.x;
  const int wave = t >> 6, lane = t & 63;
  const int m15 = lane & 15, quad = lane >> 4;
  const int b0 = blockIdx.x * 16;
  const float cst = ws[OFF_CONST];

  // ---- stage A: P[side] = tok @ W (+bias); wave = (side, nh)
  {
    const int side = wave & 1, nh = wave >> 1;
    const u16* W = side ? WB : WA;   // frag-ordered [17][2][64][8]
    const float* bias = ws + (side ? OFF_BB : OFF_BA);
    const int dd = (m15 & 3) + side * 4;
    short8 a0[4], a1[4];
#pragma unroll
    for (int mt = 0; mt < 4; mt++) {
      const int e = mt * 4 + (m15 >> 2);
      const u16* ab = tok + ((size_t)(dd * 65536 + b0 + e)) * 64 + quad * 8;
      a0[mt] = *(const short8*)ab;
      a1[mt] = *(const short8*)(ab + 32);
    }
    u16* Pb = &P[side * PSIDE2];
    // nh=0: nt 0..8 (nt=8 only mt 0..1); nh=1: nt 8..16 (nt=8 only mt 2..3)
#pragma unroll
    for (int i = 0; i < 9; i++) {
      const int nt = nh ? (8 + i) : i;
      const int mt0 = (nt == 8 && nh) ? 2 : 0;
      const int mt1 = (nt == 8 && !nh) ? 2 : 4;
      const u16* bp = W + nt * 1024 + lane * 8;   // unit-stride 1KB/wave
      short8 w0f = *(const short8*)bp;
      short8 w1f = *(const short8*)(bp + 512);
      float4 bi = *(const float4*)(bias + nt * 16 + quad * 4);
#pragma unroll
      for (int mt = 0; mt < 4; mt++) {
        if (mt < mt0 || mt >= mt1) continue;
        f32x4 acc = {0.f, 0.f, 0.f, 0.f};
        // swapped: C[m=W-col][n=token]; lane holds col n=m15, rows quad*4+r
        acc = __builtin_amdgcn_mfma_f32_16x16x32_bf16(w0f, a0[mt], acc, 0, 0, 0);
        acc = __builtin_amdgcn_mfma_f32_16x16x32_bf16(w1f, a1[mt], acc, 0, 0, 0);
        float v0 = acc[0] + bi.x, v1 = acc[1] + bi.y;
        float v2 = acc[2] + bi.z, v3 = acc[3] + bi.w;
        u32x2 pk;
        pk[0] = cvtpk(v0, v1);
        pk[1] = cvtpk(v2, v3);
        *(u32x2*)&Pb[(mt * 16 + m15) * P_STRIDE + nt * 16 + quad * 4] = pk;
        if (nt == 16 && quad < 2)   // cols 256..263: f32 folded V
          *(float4*)&Vf[side][mt * 16 + m15][quad * 4] = (float4){v0, v1, v2, v3};
      }
    }
  }
  __syncthreads();
  // ---- stage B: MFMA scores. wave = elem-group (4 elems), rows eg*16..+15
  {
    const int eg = wave;
    const int q2 = (quad & 1) * 8;
    const bool hiq = (quad & 2) != 0;          // upper-half lanes: B reads zeros
    const u16* row0 = P + (size_t)(eg * 16 + m15) * P_STRIDE;   // side 0
    const u16* row1 = row0 + PSIDE2;                             // side 1
    float acc = 0.f;
#pragma unroll
    for (int tag = 0; tag < 4; tag++) {
      const int qs = tag & 1, cross = tag >> 1;
      const int ks2 = qs ^ cross;
      const u16* rowK = ks2 ? row1 : row0;
      const u16* rowQ = qs ? row1 : row0;
      // folded-V preload (f32): rows eg*16 + quad*4 + kk, cols cross*4..+3
      float4 vv0 = *(const float4*)&Vf[ks2][eg * 16 + quad * 4 + 0][cross * 4];
      float4 vv1 = *(const float4*)&Vf[ks2][eg * 16 + quad * 4 + 1][cross * 4];
      float4 vv2 = *(const float4*)&Vf[ks2][eg * 16 + quad * 4 + 2][cross * 4];
      float4 vv3 = *(const float4*)&Vf[ks2][eg * 16 + quad * 4 + 3][cross * 4];
      float vvs[4][4] = {{vv0.x, vv0.y, vv0.z, vv0.w},
                         {vv1.x, vv1.y, vv1.z, vv1.w},
                         {vv2.x, vv2.y, vv2.z, vv2.w},
                         {vv3.x, vv3.y, vv3.z, vv3.w}};
#pragma unroll
      for (int h = 0; h < 4; h++) {
        const int kcol = 64 + cross * 128 + h * 16 + q2;
        const int qcol = hiq ? 264 : (cross * 128 + h * 16 + q2);  // 264..271 = zeros
        short8 afr = *(const short8*)(rowK + kcol);
        short8 bfr = *(const short8*)(rowQ + qcol);
        f32x4 c = {0.f, 0.f, 0.f, 0.f};
        c = __builtin_amdgcn_mfma_f32_16x16x32_bf16(afr, bfr, c, 0, 0, 0);
        // diag lanes (quad == m15>>2) hold sc[kk=0..3]; pre-scaled by log2e
        float e0 = EXP2(c[0]), e1 = EXP2(c[1]);
        float e2 = EXP2(c[2]), e3 = EXP2(c[3]);
        float o = e0 * vvs[0][h] + e1 * vvs[1][h] +
                  e2 * vvs[2][h] + e3 * vvs[3][h];
        acc += o * __builtin_amdgcn_rcpf(e0 + e1 + e2 + e3);
      }
    }
    // diag lanes sit at 20e+q (q = m15&3): xor-1/2 stays inside the q-group
    acc += __shfl_xor(acc, 1);
    acc += __shfl_xor(acc, 2);
    if (quad == (m15 >> 2) && (m15 & 3) == 0) {
      float val = 0.125f * acc + cst;
      out[b0 + eg * 4 + quad] = val > 0.f ? val : 0.01f * val;
    }
  }
}

// ---------------------------------------------------------------- launch
extern "C" void kernel_launch(void* const* d_in, const int* in_sizes, int n_in,
                              void* d_out, int out_size, void* d_ws, size_t ws_size,
                              hipStream_t stream) {
  const float* x      = (const float*)d_in[0];
  const float* w1     = (const float*)d_in[1];
  const float* b1     = (const float*)d_in[2];
  const float* w2     = (const float*)d_in[3];
  const float* b2     = (const float*)d_in[4];
  const float* w3     = (const float*)d_in[5];
  const float* b3     = (const float*)d_in[6];
  const float* win_sa = (const float*)d_in[7];
  const float* bin_sa = (const float*)d_in[8];
  const float* wo_sa  = (const float*)d_in[9];
  const float* bo_sa  = (const float*)d_in[10];
  const float* win_sb = (const float*)d_in[11];
  const float* bin_sb = (const float*)d_in[12];
  const float* wo_sb  = (const float*)d_in[13];
  const float* bo_sb  = (const float*)d_in[14];
  const float* win_ca = (const float*)d_in[15];
  const float* bin_ca = (const float*)d_in[16];
  const float* wo_ca  = (const float*)d_in[17];
  const float* bo_ca  = (const float*)d_in[18];
  const float* win_cb = (const float*)d_in[19];
  const float* bin_cb = (const float*)d_in[20];
  const float* wo_cb  = (const float*)d_in[21];
  const float* bo_cb  = (const float*)d_in[22];
  const float* Wf     = (const float*)d_in[23];
  const float* bf     = (const float*)d_in[24];
  float* ws = (float*)d_ws;
  u16* WAp    = (u16*)((char*)d_ws + OFF_WA_B);
  u16* WBp    = (u16*)((char*)d_ws + OFF_WB_B);
  u16* w2p    = (u16*)((char*)d_ws + OFF_W2P_B);
  u16* w3p    = (u16*)((char*)d_ws + OFF_W3P_B);
  u16* tokbuf = (u16*)((char*)d_ws + OFF_TOK_B);
  float* out = (float*)d_out;

  prep_fold<<<4, 64, 0, stream>>>(win_sa, bin_sa, wo_sa, bo_sa,
                                  win_sb, bin_sb, wo_sb, bo_sb,
                                  win_ca, bin_ca, wo_ca, bo_ca,
                                  win_cb, bin_cb, wo_cb, bo_cb,
                                  Wf, ws);
  prep_pack<<<907, 256, 0, stream>>>(w2, w3, win_sa, win_sb, win_ca, win_cb,
                                     bin_sa, bin_sb, bin_ca, bin_cb, bf,
                                     ws, w2p, w3p, WAp, WBp);
  tokens_kernel<<<4096, 256, 0, stream>>>(x, w1, b1, b2, b3, w2p, w3p, tokbuf);
  attn_kernel<<<4096, 256, 0, stream>>>(ws, tokbuf, WAp, WBp, out);
}

// Round 15
// 199.625 us; speedup vs baseline: 1.0109x; 1.0109x over previous
//
#include <hip/hip_runtime.h>

typedef unsigned short u16;
typedef __attribute__((ext_vector_type(8))) short short8;
typedef __attribute__((ext_vector_type(4))) short s16x4;
typedef __attribute__((ext_vector_type(4))) float f32x4;
typedef __attribute__((ext_vector_type(2))) unsigned int u32x2;

// ws float-index offsets
#define OFF_U     0       // [4][4][64] folded value vectors (tag,h,k)
#define OFF_CV    1024    // [4][4]
#define OFF_CONST 1040
#define OFF_CTAG  1044    // [4] per-tag bo.wfh sums
#define OFF_BA    1056    // [272] fp32 bias for WA cols
#define OFF_BB    1328    // [272]
// ws byte offsets (16B-aligned)
#define OFF_WA_B    6400     // u16 [17][2][64][8]  WA frag-ordered
#define OFF_WB_B    41216    // u16 [17][2][64][8]  WB frag-ordered
#define OFF_W2P_B   76032    // u16 [8][32][64][8]  w2 in frag order
#define OFF_W3P_B   338176   // u16 [8][16][64][8]  w3 in frag order
#define OFF_TOK_B   469248   // u16 tokens, D-MAJOR: [8][65536][64]

#define P_STRIDE 280
#define PSIDE2   (64 * P_STRIDE)   // 16-elem blocks: 64 rows per side

// sqrt(log2(e)): Q and K blocks of WA/WB both scaled by this in prep_pack,
// so QK^T MFMA emits log2e*score and softmax uses raw hardware 2^x.
#define SQL2E 1.2011224087864498f

#if __has_builtin(__builtin_amdgcn_exp2f)
#define EXP2(x) __builtin_amdgcn_exp2f(x)
#else
#define EXP2(x) exp2f(x)
#endif

// NOTE (R28 ledger): SCOL scratch swizzle is correctness-safe but
// PERFORMANCE-NEGATIVE here (bank conflicts 2.6M -> 14.9M, +2.3us): the
// linear layout's layer3 reads/store-stage reads were already benign and
// the XOR broke them. Do not re-apply.

static __device__ __forceinline__ u16 f2bf(float f) {
  unsigned int bits = __float_as_uint(f);
  bits += 0x7fffu + ((bits >> 16) & 1u);
  return (u16)(bits >> 16);
}
// COMPILER-NATIVE packed f32->bf16 (RNE) via the __bf16 IR type (tokens).
// R18-R20 lesson: NEVER hand-write cvt_pk asm in a kernel that also issues
// MFMA — data-dependent garbage. Native IR = safe.
static __device__ __forceinline__ unsigned pk2(float lo, float hi) {
  union { __bf16 h[2]; unsigned u; } c;
  c.h[0] = (__bf16)lo;
  c.h[1] = (__bf16)hi;
  return c.u;
}
// asm cvtpk retained ONLY for attn_kernel (harness-proven there, R3/R8).
static __device__ __forceinline__ unsigned cvtpk(float lo, float hi) {
  unsigned r;
  asm("v_cvt_pk_bf16_f32 %0, %1, %2" : "=v"(r) : "v"(lo), "v"(hi));
  return r;
}

// ---------------------------------------------------------------- prep 1: fold
// R27: own kernel (R12 inline-fold regressed prep_pack 5 -> 67us: the
// LDS-shared v, computed once per tag, is the whole point).
__global__ __launch_bounds__(64) void prep_fold(
    const float* __restrict__ win_sa, const float* __restrict__ bin_sa,
    const float* __restrict__ wo_sa,  const float* __restrict__ bo_sa,
    const float* __restrict__ win_sb, const float* __restrict__ bin_sb,
    const float* __restrict__ wo_sb,  const float* __restrict__ bo_sb,
    const float* __restrict__ win_ca, const float* __restrict__ bin_ca,
    const float* __restrict__ wo_ca,  const float* __restrict__ bo_ca,
    const float* __restrict__ win_cb, const float* __restrict__ bin_cb,
    const float* __restrict__ wo_cb,  const float* __restrict__ bo_cb,
    const float* __restrict__ Wf, float* __restrict__ ws) {
  __shared__ float v_lds[64];
  const int t = threadIdx.x;
  const int tag = blockIdx.x;
  const float* wins[4] = {win_sa, win_sb, win_ca, win_cb};
  const float* bins[4] = {bin_sa, bin_sb, bin_ca, bin_cb};
  const float* wos[4]  = {wo_sa, wo_sb, wo_ca, wo_cb};
  const float* bos[4]  = {bo_sa, bo_sb, bo_ca, bo_cb};
  const float* wfh = Wf + ((tag == 0 || tag == 2) ? 0 : 64);
  float v = 0.f;
#pragma unroll
  for (int e = 0; e < 64; e++) v += wos[tag][e * 64 + t] * wfh[e];
  v_lds[t] = v;
  __syncthreads();
#pragma unroll
  for (int h = 0; h < 4; h++) {
    float u = 0.f;
#pragma unroll
    for (int dp = 0; dp < 16; dp++)
      u += wins[tag][(128 + h * 16 + dp) * 64 + t] * v_lds[h * 16 + dp];
    ws[OFF_U + tag * 256 + h * 64 + t] = u;
  }
  if (t < 4) {
    float cv = 0.f;
#pragma unroll
    for (int dp = 0; dp < 16; dp++)
      cv += bins[tag][128 + t * 16 + dp] * v_lds[t * 16 + dp];
    ws[OFF_CV + tag * 4 + t] = cv;
  }
  if (t == 0) {
    float c = 0.f;
#pragma unroll
    for (int e = 0; e < 64; e++) c += bos[tag][e] * wfh[e];
    ws[OFF_CTAG + tag] = c;
  }
}

// ---------------------------------------------------------------- prep 2: pack
__global__ __launch_bounds__(256) void prep_pack(
    const float* __restrict__ w2, const float* __restrict__ w3,
    const float* __restrict__ win_sa, const float* __restrict__ win_sb,
    const float* __restrict__ win_ca, const float* __restrict__ win_cb,
    const float* __restrict__ bin_sa, const float* __restrict__ bin_sb,
    const float* __restrict__ bin_ca, const float* __restrict__ bin_cb,
    const float* __restrict__ bf,
    float* __restrict__ ws, u16* __restrict__ w2p, u16* __restrict__ w3p,
    u16* __restrict__ WA, u16* __restrict__ WB) {
  int idx = blockIdx.x * 256 + threadIdx.x;
  if (idx < 131072) {               // w2p[d][ks*8+nt][lane][j]
    int d = idx >> 14, rem = idx & 16383;
    int f = rem >> 9, ks = f >> 3, nt = f & 7;
    int r2 = rem & 511, l = r2 >> 3, j = r2 & 7;
    int quad = l >> 4, m15 = l & 15;
    w2p[idx] = f2bf(w2[(d * 128 + nt * 16 + m15) * 128 + ks * 32 + quad * 8 + j]);
  } else if (idx < 196608) {        // w3p[d][ks*4+nt][lane][j]
    int i = idx - 131072;
    int d = i >> 13, rem = i & 8191;
    int f = rem >> 9, ks = f >> 2, nt = f & 3;
    int r2 = rem & 511, l = r2 >> 3, j = r2 & 7;
    int quad = l >> 4, m15 = l & 15;
    w3p[i] = f2bf(w3[(d * 64 + nt * 16 + m15) * 128 + ks * 32 + quad * 8 + j]);
  } else if (idx < 214016) {        // WAf [17][2][64][8]
    int i = idx - 196608;
    int nt = i >> 10, rem = i & 1023;
    int half = rem >> 9, r2 = rem & 511, l = r2 >> 3, j = r2 & 7;
    int n = nt * 16 + (l & 15), k = half * 32 + (l >> 4) * 8 + j;
    float v;
    if (n < 64)       v = win_sa[n * 64 + k] * 0.25f;
    else if (n < 128) v = win_sa[n * 64 + k];
    else if (n < 192) v = win_ca[(n - 128) * 64 + k] * 0.25f;
    else if (n < 256) v = win_cb[(n - 128) * 64 + k];
    else if (n < 260) v = ws[OFF_U + 0 * 256 + (n - 256) * 64 + k];
    else if (n < 264) v = ws[OFF_U + 3 * 256 + (n - 260) * 64 + k];
    else              v = 0.f;
    if (n < 256) v *= SQL2E;        // fold exp->exp2 scale into Q and K blocks
    WA[i] = f2bf(v);
  } else if (idx < 231424) {        // WBf [17][2][64][8]
    int i = idx - 214016;
    int nt = i >> 10, rem = i & 1023;
    int half = rem >> 9, r2 = rem & 511, l = r2 >> 3, j = r2 & 7;
    int n = nt * 16 + (l & 15), k = half * 32 + (l >> 4) * 8 + j;
    float v;
    if (n < 64)       v = win_sb[n * 64 + k] * 0.25f;
    else if (n < 128) v = win_sb[n * 64 + k];
    else if (n < 192) v = win_cb[(n - 128) * 64 + k] * 0.25f;
    else if (n < 256) v = win_ca[(n - 128) * 64 + k];
    else if (n < 260) v = ws[OFF_U + 1 * 256 + (n - 256) * 64 + k];
    else if (n < 264) v = ws[OFF_U + 2 * 256 + (n - 260) * 64 + k];
    else              v = 0.f;
    if (n < 256) v *= SQL2E;        // fold exp->exp2 scale into Q and K blocks
    WB[i] = f2bf(v);
  } else if (idx < 231696) {        // bA
    int n = idx - 231424;
    float v;
    if (n < 64)       v = bin_sa[n] * 0.25f;
    else if (n < 128) v = bin_sa[n];
    else if (n < 192) v = bin_ca[n - 128] * 0.25f;
    else if (n < 256) v = bin_cb[n - 128];
    else if (n < 260) v = ws[OFF_CV + 0 * 4 + (n - 256)];
    else if (n < 264) v = ws[OFF_CV + 3 * 4 + (n - 260)];
    else              v = 0.f;
    if (n < 256) v *= SQL2E;
    ws[OFF_BA + n] = v;
  } else if (idx < 231968) {        // bB
    int n = idx - 231696;
    float v;
    if (n < 64)       v = bin_sb[n] * 0.25f;
    else if (n < 128) v = bin_sb[n];
    else if (n < 192) v = bin_cb[n - 128] * 0.25f;
    else if (n < 256) v = bin_ca[n - 128];
    else if (n < 260) v = ws[OFF_CV + 1 * 4 + (n - 256)];
    else if (n < 264) v = ws[OFF_CV + 2 * 4 + (n - 260)];
    else              v = 0.f;
    if (n < 256) v *= SQL2E;
    ws[OFF_BB + n] = v;
  } else if (idx == 231968) {
    ws[OFF_CONST] = 0.5f * (ws[OFF_CTAG] + ws[OFF_CTAG + 1] +
                            ws[OFF_CTAG + 2] + ws[OFF_CTAG + 3]) + bf[0];
  }
}

// ---------------------------------------------------------------- tokens (MFMA)
// R22 (frozen, harness-proven best): M=32/wave, w2/w3 STREAMED from L2,
// linear scratch (R24 LDS-staging and R28 SCOL-swizzle both regressed).
__global__ __launch_bounds__(256, 4) void tokens_kernel(
    const float* __restrict__ x, const float* __restrict__ w1,
    const float* __restrict__ b1, const float* __restrict__ b2,
    const float* __restrict__ b3, const u16* __restrict__ w2p,
    const u16* __restrict__ w3p, u16* __restrict__ tok_out) {
  __shared__ __align__(16) u16 scratch[4][32 * 136];   // h2s, then store-stage
  const int t = threadIdx.x;
  const int wave = t >> 6, lane = t & 63;
  const int m15 = lane & 15, quad = lane >> 4;
  const int d = blockIdx.x >> 9;          // d-major: co-resident blocks share w2[d]
  const int g = blockIdx.x & 511;
  const int b0 = g * 128 + wave * 32;
  const float xv0 = x[(size_t)(b0 + m15) * 8 + d];
  const float xv1 = x[(size_t)(b0 + 16 + m15) * 8 + d];

  // ---- layer2 MFMA: B-frags streamed (frag-ordered w2p), A rebuilt per ks
  const u16* w2base = w2p + d * 16384 + lane * 8;
  f32x4 acc2[2][8];
#pragma unroll
  for (int mt = 0; mt < 2; mt++)
#pragma unroll
    for (int nt = 0; nt < 8; nt++) acc2[mt][nt] = (f32x4){0.f, 0.f, 0.f, 0.f};
#pragma unroll
  for (int ks = 0; ks < 4; ks++) {
    const float* w1p = w1 + d * 128 + ks * 32 + quad * 8;
    const float* b1p = b1 + d * 128 + ks * 32 + quad * 8;
    float4 wa = *(const float4*)w1p, wb = *(const float4*)(w1p + 4);
    float4 ba = *(const float4*)b1p, bb = *(const float4*)(b1p + 4);
    union { short8 s; unsigned u[4]; } a0, a1;
    a0.u[0] = pk2(__sinf(xv0 * wa.x + ba.x), __sinf(xv0 * wa.y + ba.y));
    a0.u[1] = pk2(__sinf(xv0 * wa.z + ba.z), __sinf(xv0 * wa.w + ba.w));
    a0.u[2] = pk2(__sinf(xv0 * wb.x + bb.x), __sinf(xv0 * wb.y + bb.y));
    a0.u[3] = pk2(__sinf(xv0 * wb.z + bb.z), __sinf(xv0 * wb.w + bb.w));
    a1.u[0] = pk2(__sinf(xv1 * wa.x + ba.x), __sinf(xv1 * wa.y + ba.y));
    a1.u[1] = pk2(__sinf(xv1 * wa.z + ba.z), __sinf(xv1 * wa.w + ba.w));
    a1.u[2] = pk2(__sinf(xv1 * wb.x + bb.x), __sinf(xv1 * wb.y + bb.y));
    a1.u[3] = pk2(__sinf(xv1 * wb.z + bb.z), __sinf(xv1 * wb.w + bb.w));
#pragma unroll
    for (int nt = 0; nt < 8; nt++) {
      short8 bfr = *(const short8*)(w2base + (ks * 8 + nt) * 512);
      // swapped: C[m = w2-col][n = token]; lane holds token m15, rows quad*4+r
      acc2[0][nt] = __builtin_amdgcn_mfma_f32_16x16x32_bf16(bfr, a0.s, acc2[0][nt], 0, 0, 0);
      acc2[1][nt] = __builtin_amdgcn_mfma_f32_16x16x32_bf16(bfr, a1.s, acc2[1][nt], 0, 0, 0);
    }
  }
  // ---- ep2 -> wave-private scratch, packed 8B writes (4 consecutive h2 cols)
#pragma unroll
  for (int nt = 0; nt < 8; nt++) {
    float4 bi = *(const float4*)(b2 + d * 128 + nt * 16 + quad * 4);
#pragma unroll
    for (int mt = 0; mt < 2; mt++) {
      u32x2 pk;
      pk[0] = pk2(__sinf(acc2[mt][nt][0] + bi.x), __sinf(acc2[mt][nt][1] + bi.y));
      pk[1] = pk2(__sinf(acc2[mt][nt][2] + bi.z), __sinf(acc2[mt][nt][3] + bi.w));
      *(u32x2*)&scratch[wave][(mt * 16 + m15) * 136 + nt * 16 + quad * 4] = pk;
    }
  }
  // ---- layer3 MFMA: A from LDS (token rows), B streamed (frag-ordered w3p)
  const u16* w3base = w3p + d * 8192 + lane * 8;
  f32x4 acc3[2][4];
#pragma unroll
  for (int mt = 0; mt < 2; mt++)
#pragma unroll
    for (int nt = 0; nt < 4; nt++) acc3[mt][nt] = (f32x4){0.f, 0.f, 0.f, 0.f};
#pragma unroll
  for (int ks = 0; ks < 4; ks++) {
    short8 af0 = *(const short8*)&scratch[wave][m15 * 136 + ks * 32 + quad * 8];
    short8 af1 = *(const short8*)&scratch[wave][(16 + m15) * 136 + ks * 32 + quad * 8];
#pragma unroll
    for (int nt = 0; nt < 4; nt++) {
      short8 bfr = *(const short8*)(w3base + (ks * 4 + nt) * 512);
      acc3[0][nt] = __builtin_amdgcn_mfma_f32_16x16x32_bf16(bfr, af0, acc3[0][nt], 0, 0, 0);
      acc3[1][nt] = __builtin_amdgcn_mfma_f32_16x16x32_bf16(bfr, af1, acc3[1][nt], 0, 0, 0);
    }
  }
  // ---- ep3: packed re-stage (same-wave order-safe), then contiguous stores
#pragma unroll
  for (int nt = 0; nt < 4; nt++) {
    float4 bi = *(const float4*)(b3 + d * 64 + nt * 16 + quad * 4);
#pragma unroll
    for (int mt = 0; mt < 2; mt++) {
      u32x2 pk;
      pk[0] = pk2(acc3[mt][nt][0] + bi.x, acc3[mt][nt][1] + bi.y);
      pk[1] = pk2(acc3[mt][nt][2] + bi.z, acc3[mt][nt][3] + bi.w);
      *(u32x2*)&scratch[wave][(mt * 16 + m15) * 136 + nt * 16 + quad * 4] = pk;
    }
  }
  {
    int chunk = lane & 7;
#pragma unroll
    for (int it = 0; it < 4; it++) {
      int row_l = (lane >> 3) + it * 8;
      short8 v = *(const short8*)&scratch[wave][row_l * 136 + chunk * 8];
      *(short8*)(tok_out + ((size_t)(d * 65536 + b0 + row_l)) * 64 + chunk * 8) = v;
    }
  }
}

// ---------------------------------------------------------------- attention
// R26/R27 (frozen): R17/R8 structure + balanced 8.5/8.5 stage-A split;
// softmax via hardware 2^x (scores pre-scaled by log2e in prep_pack).
// R23 512-thr split regressed; don't re-split.
__global__ __launch_bounds__(256, 2) void attn_kernel(
    const float* __restrict__ ws, const u16* __restrict__ tok,
    const u16* __restrict__ WA, const u16* __restrict__ WB,
    float* __restrict__ out) {
  __shared__ __align__(16) u16 P[2 * PSIDE2];     // 70 KB
  __shared__ __align__(16) float Vf[2][64][12];   // 6 KB
  const int t = threadIdx.x;
  const int wave = t >> 6, lane = t & 63;
  const int m15 = lane & 15, quad = lane >> 4;
  const int b0 = blockIdx.x * 16;
  const float cst = ws[OFF_CONST];

  // ---- stage A: P[side] = tok @ W (+bias); wave = (side, nh)
  {
    const int side = wave & 1, nh = wave >> 1;
    const u16* W = side ? WB : WA;   // frag-ordered [17][2][64][8]
    const float* bias = ws + (side ? OFF_BB : OFF_BA);
    const int dd = (m15 & 3) + side * 4;
    short8 a0[4], a1[4];
#pragma unroll
    for (int mt = 0; mt < 4; mt++) {
      const int e = mt * 4 + (m15 >> 2);
      const u16* ab = tok + ((size_t)(dd * 65536 + b0 + e)) * 64 + quad * 8;
      a0[mt] = *(const short8*)ab;
      a1[mt] = *(const short8*)(ab + 32);
    }
    u16* Pb = &P[side * PSIDE2];
    // nh=0: nt 0..8 (nt=8 only mt 0..1); nh=1: nt 8..16 (nt=8 only mt 2..3)
#pragma unroll
    for (int i = 0; i < 9; i++) {
      const int nt = nh ? (8 + i) : i;
      const int mt0 = (nt == 8 && nh) ? 2 : 0;
      const int mt1 = (nt == 8 && !nh) ? 2 : 4;
      const u16* bp = W + nt * 1024 + lane * 8;   // unit-stride 1KB/wave
      short8 w0f = *(const short8*)bp;
      short8 w1f = *(const short8*)(bp + 512);
      float4 bi = *(const float4*)(bias + nt * 16 + quad * 4);
#pragma unroll
      for (int mt = 0; mt < 4; mt++) {
        if (mt < mt0 || mt >= mt1) continue;
        f32x4 acc = {0.f, 0.f, 0.f, 0.f};
        // swapped: C[m=W-col][n=token]; lane holds col n=m15, rows quad*4+r
        acc = __builtin_amdgcn_mfma_f32_16x16x32_bf16(w0f, a0[mt], acc, 0, 0, 0);
        acc = __builtin_amdgcn_mfma_f32_16x16x32_bf16(w1f, a1[mt], acc, 0, 0, 0);
        float v0 = acc[0] + bi.x, v1 = acc[1] + bi.y;
        float v2 = acc[2] + bi.z, v3 = acc[3] + bi.w;
        u32x2 pk;
        pk[0] = cvtpk(v0, v1);
        pk[1] = cvtpk(v2, v3);
        *(u32x2*)&Pb[(mt * 16 + m15) * P_STRIDE + nt * 16 + quad * 4] = pk;
        if (nt == 16 && quad < 2)   // cols 256..263: f32 folded V
          *(float4*)&Vf[side][mt * 16 + m15][quad * 4] = (float4){v0, v1, v2, v3};
      }
    }
  }
  __syncthreads();
  // ---- stage B: MFMA scores. wave = elem-group (4 elems), rows eg*16..+15
  {
    const int eg = wave;
    const int q2 = (quad & 1) * 8;
    const bool hiq = (quad & 2) != 0;          // upper-half lanes: B reads zeros
    const u16* row0 = P + (size_t)(eg * 16 + m15) * P_STRIDE;   // side 0
    const u16* row1 = row0 + PSIDE2;                             // side 1
    float acc = 0.f;
#pragma unroll
    for (int tag = 0; tag < 4; tag++) {
      const int qs = tag & 1, cross = tag >> 1;
      const int ks2 = qs ^ cross;
      const u16* rowK = ks2 ? row1 : row0;
      const u16* rowQ = qs ? row1 : row0;
      // folded-V preload (f32): rows eg*16 + quad*4 + kk, cols cross*4..+3
      float4 vv0 = *(const float4*)&Vf[ks2][eg * 16 + quad * 4 + 0][cross * 4];
      float4 vv1 = *(const float4*)&Vf[ks2][eg * 16 + quad * 4 + 1][cross * 4];
      float4 vv2 = *(const float4*)&Vf[ks2][eg * 16 + quad * 4 + 2][cross * 4];
      float4 vv3 = *(const float4*)&Vf[ks2][eg * 16 + quad * 4 + 3][cross * 4];
      float vvs[4][4] = {{vv0.x, vv0.y, vv0.z, vv0.w},
                         {vv1.x, vv1.y, vv1.z, vv1.w},
                         {vv2.x, vv2.y, vv2.z, vv2.w},
                         {vv3.x, vv3.y, vv3.z, vv3.w}};
#pragma unroll
      for (int h = 0; h < 4; h++) {
        const int kcol = 64 + cross * 128 + h * 16 + q2;
        const int qcol = hiq ? 264 : (cross * 128 + h * 16 + q2);  // 264..271 = zeros
        short8 afr = *(const short8*)(rowK + kcol);
        short8 bfr = *(const short8*)(rowQ + qcol);
        f32x4 c = {0.f, 0.f, 0.f, 0.f};
        c = __builtin_amdgcn_mfma_f32_16x16x32_bf16(afr, bfr, c, 0, 0, 0);
        // diag lanes (quad == m15>>2) hold sc[kk=0..3]; pre-scaled by log2e
        float e0 = EXP2(c[0]), e1 = EXP2(c[1]);
        float e2 = EXP2(c[2]), e3 = EXP2(c[3]);
        float o = e0 * vvs[0][h] + e1 * vvs[1][h] +
                  e2 * vvs[2][h] + e3 * vvs[3][h];
        acc += o * __builtin_amdgcn_rcpf(e0 + e1 + e2 + e3);
      }
    }
    // diag lanes sit at 20e+q (q = m15&3): xor-1/2 stays inside the q-group
    acc += __shfl_xor(acc, 1);
    acc += __shfl_xor(acc, 2);
    if (quad == (m15 >> 2) && (m15 & 3) == 0) {
      float val = 0.125f * acc + cst;
      out[b0 + eg * 4 + quad] = val > 0.f ? val : 0.01f * val;
    }
  }
}

// ---------------------------------------------------------------- launch
extern "C" void kernel_launch(void* const* d_in, const int* in_sizes, int n_in,
                              void* d_out, int out_size, void* d_ws, size_t ws_size,
                              hipStream_t stream) {
  const float* x      = (const float*)d_in[0];
  const float* w1     = (const float*)d_in[1];
  const float* b1     = (const float*)d_in[2];
  const float* w2     = (const float*)d_in[3];
  const float* b2     = (const float*)d_in[4];
  const float* w3     = (const float*)d_in[5];
  const float* b3     = (const float*)d_in[6];
  const float* win_sa = (const float*)d_in[7];
  const float* bin_sa = (const float*)d_in[8];
  const float* wo_sa  = (const float*)d_in[9];
  const float* bo_sa  = (const float*)d_in[10];
  const float* win_sb = (const float*)d_in[11];
  const float* bin_sb = (const float*)d_in[12];
  const float* wo_sb  = (const float*)d_in[13];
  const float* bo_sb  = (const float*)d_in[14];
  const float* win_ca = (const float*)d_in[15];
  const float* bin_ca = (const float*)d_in[16];
  const float* wo_ca  = (const float*)d_in[17];
  const float* bo_ca  = (const float*)d_in[18];
  const float* win_cb = (const float*)d_in[19];
  const float* bin_cb = (const float*)d_in[20];
  const float* wo_cb  = (const float*)d_in[21];
  const float* bo_cb  = (const float*)d_in[22];
  const float* Wf     = (const float*)d_in[23];
  const float* bf     = (const float*)d_in[24];
  float* ws = (float*)d_ws;
  u16* WAp    = (u16*)((char*)d_ws + OFF_WA_B);
  u16* WBp    = (u16*)((char*)d_ws + OFF_WB_B);
  u16* w2p    = (u16*)((char*)d_ws + OFF_W2P_B);
  u16* w3p    = (u16*)((char*)d_ws + OFF_W3P_B);
  u16* tokbuf = (u16*)((char*)d_ws + OFF_TOK_B);
  float* out = (float*)d_out;

  prep_fold<<<4, 64, 0, stream>>>(win_sa, bin_sa, wo_sa, bo_sa,
                                  win_sb, bin_sb, wo_sb, bo_sb,
                                  win_ca, bin_ca, wo_ca, bo_ca,
                                  win_cb, bin_cb, wo_cb, bo_cb,
                                  Wf, ws);
  prep_pack<<<907, 256, 0, stream>>>(w2, w3, win_sa, win_sb, win_ca, win_cb,
                                     bin_sa, bin_sb, bin_ca, bin_cb, bf,
                                     ws, w2p, w3p, WAp, WBp);
  tokens_kernel<<<4096, 256, 0, stream>>>(x, w1, b1, b2, b3, w2p, w3p, tokbuf);
  attn_kernel<<<4096, 256, 0, stream>>>(ws, tokbuf, WAp, WBp, out);
}